// Round 4
// baseline (145.757 us; speedup 1.0000x reference)
//
#include <hip/hip_runtime.h>
#include <hip/hip_bf16.h>

#define B_   8
#define N_   10000
#define H_   128
#define DIN_ 256
#define E_   160000

typedef unsigned int uint_;
typedef unsigned short ushort_;
typedef __attribute__((ext_vector_type(8))) short short8;
typedef __attribute__((ext_vector_type(4))) float f32x4;

__device__ __forceinline__ float sigmoidf_(float v) { return 1.f / (1.f + __expf(-v)); }
// tanh via exp, safe at +/-inf
__device__ __forceinline__ float tanh_fast(float v) { float e = __expf(2.f * v); return 1.f - 2.f / (e + 1.f); }

__device__ __forceinline__ ushort_ f2bf(float f) {
    union { float f; uint_ u; } v; v.f = f;
    uint_ r = v.u + 0x7fff + ((v.u >> 16) & 1);   // round-to-nearest-even
    return (ushort_)(r >> 16);
}
#define BF_LO(u) __uint_as_float((u) << 16)
#define BF_HI(u) __uint_as_float((u) & 0xffff0000u)

// ---- degrees ------------------------------------------------------------
__global__ __launch_bounds__(256) void degrees_k(const int* __restrict__ src, const int* __restrict__ dst,
                                                 int* __restrict__ out_deg, int* __restrict__ in_deg) {
    int e = blockIdx.x * 256 + threadIdx.x;
    if (e < E_) {
        atomicAdd(&out_deg[src[e]], 1);
        atomicAdd(&in_deg[dst[e]], 1);
    }
}

// ---- norms + exclusive scan of in_deg -> CSR row offsets ----------------
__global__ __launch_bounds__(1024) void norms_scan_k(const int* __restrict__ out_deg, const int* __restrict__ in_deg,
                                                     float* __restrict__ norm_out, float* __restrict__ norm_in,
                                                     int* __restrict__ offsets) {
    __shared__ int part[1024];
    const int tid = threadIdx.x;
    const int CH = 10;               // 1024*10 >= 10000
    int base = tid * CH;
    int local[CH];
    int s = 0;
    #pragma unroll
    for (int q = 0; q < CH; ++q) {
        int n = base + q;
        int d = (n < N_) ? in_deg[n] : 0;
        local[q] = s;
        s += d;
        if (n < N_) {
            int od = out_deg[n];
            norm_out[n] = od > 0 ? rsqrtf((float)od) : 0.f;
            norm_in[n]  = d  > 0 ? rsqrtf((float)d)  : 0.f;
        }
    }
    part[tid] = s;
    __syncthreads();
    for (int off = 1; off < 1024; off <<= 1) {
        int v = (tid >= off) ? part[tid - off] : 0;
        __syncthreads();
        part[tid] += v;
        __syncthreads();
    }
    int pre = (tid > 0) ? part[tid - 1] : 0;
    #pragma unroll
    for (int q = 0; q < CH; ++q) {
        int n = base + q;
        if (n < N_) offsets[n] = pre + local[q];
    }
    if (tid == 1023) offsets[N_] = part[1023];
}

// ---- bucket-fill CSR (order within bucket arbitrary; fp tolerance ok) ---
__global__ __launch_bounds__(256) void fill_csr_k(const int* __restrict__ src, const int* __restrict__ dst,
                                                  const int* __restrict__ offsets, int* __restrict__ cursor,
                                                  const float* __restrict__ norm_out,
                                                  int* __restrict__ csr_src, float* __restrict__ csr_coef) {
    int e = blockIdx.x * 256 + threadIdx.x;
    if (e < E_) {
        int d = dst[e];
        int s = src[e];
        int pos = offsets[d] + atomicAdd(&cursor[d], 1);
        csr_src[pos]  = s;
        csr_coef[pos] = norm_out[s];
    }
}

// ---- x projections + W^T cast: grid (4, 8); g==3 does wt transpose ------
__global__ __launch_bounds__(256) void xproj_k(const float* __restrict__ x,
                                               const float* __restrict__ w_r, const float* __restrict__ b_r,
                                               const float* __restrict__ w_z, const float* __restrict__ b_z,
                                               const float* __restrict__ w_h, const float* __restrict__ b_h,
                                               const float* __restrict__ gcn_w, ushort_* __restrict__ wt,
                                               float* __restrict__ xr, float* __restrict__ xz, float* __restrict__ xh) {
    const int g = blockIdx.x, b = blockIdx.y;
    if (g == 3) {                    // transpose + cast gcn_w (k,n) -> WT (n,k) bf16
        if (b != 0) return;
        const int t = threadIdx.x;
        const int n = t >> 1;
        const int kb = (t & 1) * 64;
        #pragma unroll
        for (int i = 0; i < 8; ++i) {
            int k = kb + i * 8;
            uint4 o;
            o.x = (uint_)f2bf(gcn_w[(k + 0) * H_ + n]) | ((uint_)f2bf(gcn_w[(k + 1) * H_ + n]) << 16);
            o.y = (uint_)f2bf(gcn_w[(k + 2) * H_ + n]) | ((uint_)f2bf(gcn_w[(k + 3) * H_ + n]) << 16);
            o.z = (uint_)f2bf(gcn_w[(k + 4) * H_ + n]) | ((uint_)f2bf(gcn_w[(k + 5) * H_ + n]) << 16);
            o.w = (uint_)f2bf(gcn_w[(k + 6) * H_ + n]) | ((uint_)f2bf(gcn_w[(k + 7) * H_ + n]) << 16);
            *(uint4*)(wt + n * H_ + k) = o;
        }
        return;
    }
    const float* __restrict__ w  = g == 0 ? w_r : (g == 1 ? w_z : w_h);
    const float* __restrict__ bs = g == 0 ? b_r : (g == 1 ? b_z : b_h);
    float* __restrict__ o        = g == 0 ? xr  : (g == 1 ? xz  : xh);
    const int k = threadIdx.x & 127, half = threadIdx.x >> 7;
    const float* xb = x + b * DIN_;
    float a = 0.f;
    #pragma unroll 8
    for (int d = half * 128; d < half * 128 + 128; ++d)
        a += xb[d] * w[d * H_ + k];
    __shared__ float part[2][128];
    part[half][k] = a;
    __syncthreads();
    if (half == 0) o[b * H_ + k] = a + part[1][k] + bs[k];
}

// ---- GEMM-first: hw = bf16(h_prev @ gcn_w) ------------------------------
// LDS-free A/B paths: A-fragment = coalesced direct fp32 read of h (each
// element cast exactly once, in registers); B-fragment = direct read of
// 32KB L1-resident wt. LDS (16 KB) only for the output transpose.
// Grid (8, 157): linear_id & 7 = batch -> hw slab written on the XCD that
// agg_gru_k later reads it from (warm L2).
__global__ __launch_bounds__(256) void gemm_cast_k(const float* __restrict__ h,
                                                   const ushort_* __restrict__ wt,
                                                   ushort_* __restrict__ hw) {
    __shared__ ushort_ T_s[64 * H_];    // output transpose staging, 16 KB
    const int tid = threadIdx.x;
    const int b  = blockIdx.x;          // batch (0..7) == XCD
    const int n0 = blockIdx.y * 64;     // node tile base (157 tiles, last partial)
    const size_t rbase = (size_t)b * N_ + n0;

    const int l = tid & 63;
    const int w = tid >> 6;
    const int lr = l & 15;
    const int kg = (l >> 4) * 8;        // k-offset (elements)
    const int arow = w * 16 + lr;
    const bool va = (n0 + arow) < N_;

    // A fragments: direct global read + cast (per instr: 16 rows x 128B, coalesced)
    short8 av[4];
    #pragma unroll
    for (int kk = 0; kk < 4; ++kk) {
        f32x4 v0 = {0.f, 0.f, 0.f, 0.f}, v1 = {0.f, 0.f, 0.f, 0.f};
        if (va) {
            const float* p = h + (rbase + arow) * (size_t)H_ + kk * 32 + kg;
            v0 = *(const f32x4*)p;
            v1 = *(const f32x4*)(p + 4);
        }
        union { uint4 u; short8 s; } pk;
        pk.u.x = (uint_)f2bf(v0[0]) | ((uint_)f2bf(v0[1]) << 16);
        pk.u.y = (uint_)f2bf(v0[2]) | ((uint_)f2bf(v0[3]) << 16);
        pk.u.z = (uint_)f2bf(v1[0]) | ((uint_)f2bf(v1[1]) << 16);
        pk.u.w = (uint_)f2bf(v1[2]) | ((uint_)f2bf(v1[3]) << 16);
        av[kk] = pk.s;
    }

    f32x4 acc[8];
    #pragma unroll
    for (int nf = 0; nf < 8; ++nf) acc[nf] = (f32x4){0.f, 0.f, 0.f, 0.f};

    #pragma unroll
    for (int kk = 0; kk < 4; ++kk) {
        #pragma unroll
        for (int nf = 0; nf < 8; ++nf) {
            short8 bv = *(const short8*)&wt[(nf * 16 + lr) * H_ + kk * 32 + kg];
            acc[nf] = __builtin_amdgcn_mfma_f32_16x16x32_bf16(av[kk], bv, acc[nf], 0, 0, 0);
        }
    }

    // epilogue: C/D layout col = lane&15, row = (lane>>4)*4 + r (m89).
    // Scatter acc into T_s as bf16 (swizzled), read back row-contiguous.
    const int wrow0 = w * 16 + (l >> 4) * 4;
    #pragma unroll
    for (int nf = 0; nf < 8; ++nf) {
        int col = nf * 16 + lr;
        #pragma unroll
        for (int r = 0; r < 4; ++r) {
            int row = wrow0 + r;
            T_s[row * H_ + (col ^ ((row & 7) << 3))] = f2bf(acc[nf][r]);
        }
    }
    __syncthreads();
    {
        int row = w * 16 + (l >> 2);      // 16 rows x 4 col-groups per wave
        int c0 = (l & 3) * 32;            // 32 ushorts = 64B per lane
        int swz = (row & 7) << 3;
        if (n0 + row < N_) {
            uint4 o0 = *(const uint4*)&T_s[row * H_ + ((c0 +  0) ^ swz)];
            uint4 o1 = *(const uint4*)&T_s[row * H_ + ((c0 +  8) ^ swz)];
            uint4 o2 = *(const uint4*)&T_s[row * H_ + ((c0 + 16) ^ swz)];
            uint4 o3 = *(const uint4*)&T_s[row * H_ + ((c0 + 24) ^ swz)];
            uint4* dst = (uint4*)(hw + (rbase + row) * (size_t)H_ + c0);
            dst[0] = o0; dst[1] = o1; dst[2] = o2; dst[3] = o3;
        }
    }
}

#define FMA8(A, c, u)                                       \
    A[0] += (c) * BF_LO((u).x); A[1] += (c) * BF_HI((u).x); \
    A[2] += (c) * BF_LO((u).y); A[3] += (c) * BF_HI((u).y); \
    A[4] += (c) * BF_LO((u).z); A[5] += (c) * BF_HI((u).z); \
    A[6] += (c) * BF_LO((u).w); A[7] += (c) * BF_HI((u).w);

// ---- aggregation of hw + fused GRU, one batch per XCD -------------------
// Wave = one (node, batch); batch = blockIdx.x & 7 pins each batch's 2.56MB
// hw slice to one XCD's L2. Edge list preloaded once (2 coalesced loads
// cover 64 edges; coef zero-filled past dc so no bounds cndmasks), then
// broadcast per-slot via __shfl (bpermute ~30cyc vs load ~200cyc).
// 4 independent 16B gathers in flight per iter = 16 edges (avg node: 1 iter).
__global__ __launch_bounds__(256) void agg_gru_k(const ushort_* __restrict__ hw, const int* __restrict__ offsets,
                                                 const float* __restrict__ norm_in,
                                                 const int* __restrict__ csr_src, const float* __restrict__ csr_coef,
                                                 const float* __restrict__ gcn_b,
                                                 const float* __restrict__ xr, const float* __restrict__ xz,
                                                 const float* __restrict__ xh,
                                                 const float* __restrict__ h_prev, float* __restrict__ out) {
    const int lane = threadIdx.x & 63;
    const int wave = threadIdx.x >> 6;
    const int b  = blockIdx.x & 7;                  // XCD-pinned batch
    const int ng = blockIdx.x >> 3;                 // node group (0..2499)
    const int n  = ng * 4 + wave;
    const int e  = lane >> 4;                       // edge slot
    const int c  = lane & 15;                       // col chunk (8 bf16)
    const ushort_* __restrict__ hb = hw + (size_t)b * (N_ * H_) + c * 8;
    int o  = offsets[n];
    int dc = offsets[n + 1] - o;
    float a[8];
    #pragma unroll
    for (int k = 0; k < 8; ++k) a[k] = 0.f;
    for (int base = 0; base < dc; base += 64) {
        int rem = dc - base;
        int   sp = 0; float cp = 0.f;
        if (lane < rem) {                           // coef=0 past dc -> slots no-op
            sp = csr_src[o + base + lane];
            cp = csr_coef[o + base + lane];
        }
        int lim = rem < 64 ? rem : 64;
        for (int j = 0; j < lim; j += 16) {         // q = j+e+{0,4,8,12} < 64 always
            int   s0 = __shfl(sp, j + e);
            int   s1 = __shfl(sp, j + e + 4);
            int   s2 = __shfl(sp, j + e + 8);
            int   s3 = __shfl(sp, j + e + 12);
            float f0 = __shfl(cp, j + e);
            float f1 = __shfl(cp, j + e + 4);
            float f2 = __shfl(cp, j + e + 8);
            float f3 = __shfl(cp, j + e + 12);
            uint4 u0 = *(const uint4*)(hb + (size_t)s0 * H_);
            uint4 u1 = *(const uint4*)(hb + (size_t)s1 * H_);
            uint4 u2 = *(const uint4*)(hb + (size_t)s2 * H_);
            uint4 u3 = *(const uint4*)(hb + (size_t)s3 * H_);
            FMA8(a, f0, u0);
            FMA8(a, f1, u1);
            FMA8(a, f2, u2);
            FMA8(a, f3, u3);
        }
    }
    // fold the 4 edge slots (lane bits 4,5)
    #pragma unroll
    for (int k = 0; k < 8; ++k) {
        a[k] += __shfl_xor(a[k], 16);
        a[k] += __shfl_xor(a[k], 32);
    }
    // each lane finishes 2 columns: col = c*8 + e*2 (static acc selection)
    float a0 = (e == 0) ? a[0] : (e == 1) ? a[2] : (e == 2) ? a[4] : a[6];
    float a1 = (e == 0) ? a[1] : (e == 1) ? a[3] : (e == 2) ? a[5] : a[7];
    float ni = norm_in[n];
    int col = c * 8 + e * 2;
    size_t off = ((size_t)b * N_ + n) * H_ + col;
    float2 hp = *(const float2*)(h_prev + off);
    float2 gb = *(const float2*)(gcn_b + col);
    float2 vr = *(const float2*)(xr + b * H_ + col);
    float2 vz = *(const float2*)(xz + b * H_ + col);
    float2 vh = *(const float2*)(xh + b * H_ + col);
    float2 wv;
    {
        float hc = a0 * ni + gb.x;
        float rr = sigmoidf_(vr.x + hc);
        float zz = sigmoidf_(vz.x + hc);
        float ht = tanh_fast(vh.x + rr * hc);
        wv.x = (1.f - zz) * hp.x + zz * ht;
    }
    {
        float hc = a1 * ni + gb.y;
        float rr = sigmoidf_(vr.y + hc);
        float zz = sigmoidf_(vz.y + hc);
        float ht = tanh_fast(vh.y + rr * hc);
        wv.y = (1.f - zz) * hp.y + zz * ht;
    }
    *(float2*)(out + off) = wv;
}

extern "C" void kernel_launch(void* const* d_in, const int* in_sizes, int n_in,
                              void* d_out, int out_size, void* d_ws, size_t ws_size,
                              hipStream_t stream) {
    (void)in_sizes; (void)n_in; (void)out_size; (void)ws_size;
    const float* x      = (const float*)d_in[0];
    const float* h_prev = (const float*)d_in[1];
    const int*   src    = (const int*)d_in[2];
    const int*   dst    = (const int*)d_in[3];
    const float* w_r    = (const float*)d_in[4];
    const float* b_r    = (const float*)d_in[5];
    const float* w_z    = (const float*)d_in[6];
    const float* b_z    = (const float*)d_in[7];
    const float* w_h    = (const float*)d_in[8];
    const float* b_h    = (const float*)d_in[9];
    const float* gcn_w  = (const float*)d_in[10];
    const float* gcn_b  = (const float*)d_in[11];
    float* out = (float*)d_out;

    ushort_* hw = (ushort_*)d_ws;                        // B*N*H bf16 = 20.48 MB
    int* wsi = (int*)(hw + (size_t)B_ * N_ * H_);
    int* out_deg   = wsi;                       // N
    int* in_deg    = wsi + N_;                  // N
    int* cursor    = wsi + 2 * N_;              // N
    int* offsets   = wsi + 3 * N_;              // N+1
    float* norm_out = (float*)(wsi + 4 * N_ + 1);  // N
    float* norm_in  = norm_out + N_;               // N
    int*   csr_src  = (int*)(norm_in + N_);        // E
    float* csr_coef = (float*)(csr_src + E_);      // E
    float* xr = csr_coef + E_;                     // B*H
    float* xz = xr + B_ * H_;
    float* xh = xz + B_ * H_;
    ushort_* wt = (ushort_*)(xh + B_ * H_);        // H*H bf16 = 32 KB

    hipMemsetAsync(out_deg, 0, 3 * N_ * sizeof(int), stream);  // out_deg, in_deg, cursor
    degrees_k<<<(E_ + 255) / 256, 256, 0, stream>>>(src, dst, out_deg, in_deg);
    norms_scan_k<<<1, 1024, 0, stream>>>(out_deg, in_deg, norm_out, norm_in, offsets);
    fill_csr_k<<<(E_ + 255) / 256, 256, 0, stream>>>(src, dst, offsets, cursor, norm_out, csr_src, csr_coef);
    xproj_k<<<dim3(4, B_), 256, 0, stream>>>(x, w_r, b_r, w_z, b_z, w_h, b_h, gcn_w, wt, xr, xz, xh);
    gemm_cast_k<<<dim3(8, (N_ + 63) / 64), 256, 0, stream>>>(h_prev, wt, hw);
    agg_gru_k<<<(N_ / 4) * 8, 256, 0, stream>>>(hw, offsets, norm_in, csr_src, csr_coef,
                                                gcn_b, xr, xz, xh, h_prev, out);
}

// Round 5
// 124.183 us; speedup vs baseline: 1.1737x; 1.1737x over previous
//
#include <hip/hip_runtime.h>
#include <hip/hip_bf16.h>

#define B_   8
#define N_   10000
#define H_   128
#define DIN_ 256
#define E_   160000

typedef unsigned int uint_;
typedef unsigned short ushort_;
typedef __attribute__((ext_vector_type(8))) short short8;
typedef __attribute__((ext_vector_type(4))) float f32x4;

__device__ __forceinline__ float sigmoidf_(float v) { return 1.f / (1.f + __expf(-v)); }
// tanh via exp, safe at +/-inf
__device__ __forceinline__ float tanh_fast(float v) { float e = __expf(2.f * v); return 1.f - 2.f / (e + 1.f); }

__device__ __forceinline__ ushort_ f2bf(float f) {
    union { float f; uint_ u; } v; v.f = f;
    uint_ r = v.u + 0x7fff + ((v.u >> 16) & 1);   // round-to-nearest-even
    return (ushort_)(r >> 16);
}
#define BF_LO(u) __uint_as_float((u) << 16)
#define BF_HI(u) __uint_as_float((u) & 0xffff0000u)

// ---- degrees ------------------------------------------------------------
__global__ __launch_bounds__(256) void degrees_k(const int* __restrict__ src, const int* __restrict__ dst,
                                                 int* __restrict__ out_deg, int* __restrict__ in_deg) {
    int e = blockIdx.x * 256 + threadIdx.x;
    if (e < E_) {
        atomicAdd(&out_deg[src[e]], 1);
        atomicAdd(&in_deg[dst[e]], 1);
    }
}

// ---- norms + exclusive scan of in_deg -> CSR row offsets ----------------
// All global I/O coalesced (thread-contiguous chunks live only in LDS).
__global__ __launch_bounds__(1024) void norms_scan_k(const int* __restrict__ out_deg, const int* __restrict__ in_deg,
                                                     float* __restrict__ norm_out, float* __restrict__ norm_in,
                                                     int* __restrict__ offsets) {
    __shared__ int buf[10240];       // 40 KB
    __shared__ int part[1024];
    const int tid = threadIdx.x;
    // phase A: coalesced load of in_deg into LDS + coalesced norm writes
    #pragma unroll
    for (int q = 0; q < 10; ++q) {
        int idx = q * 1024 + tid;
        int d = (idx < N_) ? in_deg[idx] : 0;
        buf[idx] = d;
        if (idx < N_) {
            int od = out_deg[idx];
            norm_out[idx] = od > 0 ? rsqrtf((float)od) : 0.f;
            norm_in[idx]  = d  > 0 ? rsqrtf((float)d)  : 0.f;
        }
    }
    __syncthreads();
    // phase B: per-thread scan of its contiguous 10-chunk (from LDS)
    int local[10];
    int s = 0;
    #pragma unroll
    for (int q = 0; q < 10; ++q) {
        local[q] = s;
        s += buf[tid * 10 + q];
    }
    part[tid] = s;
    __syncthreads();
    // phase C: block scan of partials
    for (int off = 1; off < 1024; off <<= 1) {
        int v = (tid >= off) ? part[tid - off] : 0;
        __syncthreads();
        part[tid] += v;
        __syncthreads();
    }
    int pre = (tid > 0) ? part[tid - 1] : 0;
    // phase D: write results into LDS, then coalesced store
    #pragma unroll
    for (int q = 0; q < 10; ++q)
        buf[tid * 10 + q] = pre + local[q];
    __syncthreads();
    #pragma unroll
    for (int q = 0; q < 10; ++q) {
        int idx = q * 1024 + tid;
        if (idx < N_) offsets[idx] = buf[idx];
    }
    if (tid == 1023) offsets[N_] = part[1023];
}

// ---- bucket-fill CSR (order within bucket arbitrary; fp tolerance ok) ---
__global__ __launch_bounds__(256) void fill_csr_k(const int* __restrict__ src, const int* __restrict__ dst,
                                                  const int* __restrict__ offsets, int* __restrict__ cursor,
                                                  const float* __restrict__ norm_out,
                                                  int* __restrict__ csr_src, float* __restrict__ csr_coef) {
    int e = blockIdx.x * 256 + threadIdx.x;
    if (e < E_) {
        int d = dst[e];
        int s = src[e];
        int pos = offsets[d] + atomicAdd(&cursor[d], 1);
        csr_src[pos]  = s;
        csr_coef[pos] = norm_out[s];
    }
}

// ---- x projections + W^T cast: grid (4, 8); g==3 does wt transpose ------
__global__ __launch_bounds__(256) void xproj_k(const float* __restrict__ x,
                                               const float* __restrict__ w_r, const float* __restrict__ b_r,
                                               const float* __restrict__ w_z, const float* __restrict__ b_z,
                                               const float* __restrict__ w_h, const float* __restrict__ b_h,
                                               const float* __restrict__ gcn_w, ushort_* __restrict__ wt,
                                               float* __restrict__ xr, float* __restrict__ xz, float* __restrict__ xh) {
    const int g = blockIdx.x, b = blockIdx.y;
    if (g == 3) {                    // transpose + cast gcn_w (k,n) -> WT (n,k) bf16
        if (b != 0) return;
        const int t = threadIdx.x;
        const int n = t >> 1;
        const int kb = (t & 1) * 64;
        #pragma unroll
        for (int i = 0; i < 8; ++i) {
            int k = kb + i * 8;
            uint4 o;
            o.x = (uint_)f2bf(gcn_w[(k + 0) * H_ + n]) | ((uint_)f2bf(gcn_w[(k + 1) * H_ + n]) << 16);
            o.y = (uint_)f2bf(gcn_w[(k + 2) * H_ + n]) | ((uint_)f2bf(gcn_w[(k + 3) * H_ + n]) << 16);
            o.z = (uint_)f2bf(gcn_w[(k + 4) * H_ + n]) | ((uint_)f2bf(gcn_w[(k + 5) * H_ + n]) << 16);
            o.w = (uint_)f2bf(gcn_w[(k + 6) * H_ + n]) | ((uint_)f2bf(gcn_w[(k + 7) * H_ + n]) << 16);
            *(uint4*)(wt + n * H_ + k) = o;
        }
        return;
    }
    const float* __restrict__ w  = g == 0 ? w_r : (g == 1 ? w_z : w_h);
    const float* __restrict__ bs = g == 0 ? b_r : (g == 1 ? b_z : b_h);
    float* __restrict__ o        = g == 0 ? xr  : (g == 1 ? xz  : xh);
    const int k = threadIdx.x & 127, half = threadIdx.x >> 7;
    const float* xb = x + b * DIN_;
    float a = 0.f;
    #pragma unroll 8
    for (int d = half * 128; d < half * 128 + 128; ++d)
        a += xb[d] * w[d * H_ + k];
    __shared__ float part[2][128];
    part[half][k] = a;
    __syncthreads();
    if (half == 0) o[b * H_ + k] = a + part[1][k] + bs[k];
}

// ---- GEMM-first: hw = bf16(h_prev @ gcn_w) ------------------------------
// LDS-staged (r3 structure, proven) + batch-pinned grid (8, 79):
// blockIdx.x = batch -> hw slab written on the XCD agg reads it from.
// Each block loops 2 node-tiles (t, t+79), staging the 32KB WT ONCE.
__global__ __launch_bounds__(256) void gemm_cast_k(const float* __restrict__ h,
                                                   const ushort_* __restrict__ wt,
                                                   ushort_* __restrict__ hw) {
    __shared__ ushort_ WT_s[H_ * H_];   // [n][k] bf16, swizzled: 32 KB
    __shared__ ushort_ A_s[64 * H_];    // [row][k] bf16, swizzled: 16 KB
    const int tid = threadIdx.x;
    const int b = blockIdx.x;           // batch (0..7) == XCD
    const size_t bslab = (size_t)b * N_;

    // stage W^T once: 2048 16B-chunks; swizzle k-ushorts by ((n&7)<<3)
    #pragma unroll
    for (int i = 0; i < 8; ++i) {
        int c = i * 256 + tid;
        int n = c >> 4;
        int kus = (c & 15) * 8;
        uint4 v = ((const uint4*)wt)[c];
        *(uint4*)&WT_s[n * H_ + (kus ^ ((n & 7) << 3))] = v;
    }

    const int l = tid & 63;
    const int w = tid >> 6;
    const int lr = l & 15;
    const int kg = (l >> 4) * 8;
    const int arow = w * 16 + lr;

    for (int t = blockIdx.y; t < 157; t += 79) {    // tiles 0..156 (157 = ceil(N/64))
        const int n0 = t * 64;
        // stage A tile: 64x128 fp32 rows of h -> bf16, swizzled (guarded)
        #pragma unroll
        for (int i = 0; i < 8; ++i) {
            int f4 = i * 256 + tid;           // float4 id within tile (0..2047)
            int row = f4 >> 5;
            int col4 = (f4 & 31) * 4;
            f32x4 v = {0.f, 0.f, 0.f, 0.f};
            if (n0 + row < N_) v = *(const f32x4*)&h[(bslab + n0 + row) * H_ + col4];
            uint2 p;
            p.x = (uint_)f2bf(v[0]) | ((uint_)f2bf(v[1]) << 16);
            p.y = (uint_)f2bf(v[2]) | ((uint_)f2bf(v[3]) << 16);
            *(uint2*)&A_s[row * H_ + (col4 ^ ((row & 7) << 3))] = p;
        }
        __syncthreads();

        f32x4 acc[8];
        #pragma unroll
        for (int nf = 0; nf < 8; ++nf) acc[nf] = (f32x4){0.f, 0.f, 0.f, 0.f};

        #pragma unroll
        for (int kk = 0; kk < 4; ++kk) {
            int kus = kk * 32 + kg;
            short8 av = *(const short8*)&A_s[arow * H_ + (kus ^ ((arow & 7) << 3))];
            #pragma unroll
            for (int nf = 0; nf < 8; ++nf) {
                int nrow = nf * 16 + lr;
                short8 bv = *(const short8*)&WT_s[nrow * H_ + (kus ^ ((nrow & 7) << 3))];
                acc[nf] = __builtin_amdgcn_mfma_f32_16x16x32_bf16(av, bv, acc[nf], 0, 0, 0);
            }
        }

        // epilogue: C/D layout col = lane&15, row = (lane>>4)*4 + r (m89).
        // Scatter acc into own wave's A_s rows (per-wave disjoint), then
        // read back row-contiguous for coalesced 64B/lane global stores.
        const int wrow0 = w * 16 + (l >> 4) * 4;
        #pragma unroll
        for (int nf = 0; nf < 8; ++nf) {
            int col = nf * 16 + lr;
            #pragma unroll
            for (int r = 0; r < 4; ++r) {
                int row = wrow0 + r;
                A_s[row * H_ + (col ^ ((row & 7) << 3))] = f2bf(acc[nf][r]);
            }
        }
        __syncthreads();   // cross-lane LDS transpose: make visibility explicit
        {
            int row = w * 16 + (l >> 2);      // 16 rows x 4 col-groups per wave
            int c0 = (l & 3) * 32;            // 32 ushorts = 64B per lane
            int swz = (row & 7) << 3;
            if (n0 + row < N_) {
                uint4 o0 = *(const uint4*)&A_s[row * H_ + ((c0 +  0) ^ swz)];
                uint4 o1 = *(const uint4*)&A_s[row * H_ + ((c0 +  8) ^ swz)];
                uint4 o2 = *(const uint4*)&A_s[row * H_ + ((c0 + 16) ^ swz)];
                uint4 o3 = *(const uint4*)&A_s[row * H_ + ((c0 + 24) ^ swz)];
                uint4* dst = (uint4*)(hw + (bslab + n0 + row) * (size_t)H_ + c0);
                dst[0] = o0; dst[1] = o1; dst[2] = o2; dst[3] = o3;
            }
        }
        __syncthreads();   // A_s reused next tile iteration
    }
}

#define FMA8(A, c, u)                                       \
    A[0] += (c) * BF_LO((u).x); A[1] += (c) * BF_HI((u).x); \
    A[2] += (c) * BF_LO((u).y); A[3] += (c) * BF_HI((u).y); \
    A[4] += (c) * BF_LO((u).z); A[5] += (c) * BF_HI((u).z); \
    A[6] += (c) * BF_LO((u).w); A[7] += (c) * BF_HI((u).w);

// ---- aggregation of hw + fused GRU, one batch per XCD -------------------
// Wave = one (node, batch); batch = blockIdx.x & 7 pins each batch's 2.56MB
// hw slice to one XCD's L2. Edge list preloaded once (2 coalesced loads
// cover 64 edges; coef zero-filled past dc), broadcast per-slot via __shfl.
// Epilogue operands hoisted BEFORE the gather loop so their HBM latency
// overlaps the gather chain.
__global__ __launch_bounds__(256) void agg_gru_k(const ushort_* __restrict__ hw, const int* __restrict__ offsets,
                                                 const float* __restrict__ norm_in,
                                                 const int* __restrict__ csr_src, const float* __restrict__ csr_coef,
                                                 const float* __restrict__ gcn_b,
                                                 const float* __restrict__ xr, const float* __restrict__ xz,
                                                 const float* __restrict__ xh,
                                                 const float* __restrict__ h_prev, float* __restrict__ out) {
    const int lane = threadIdx.x & 63;
    const int wave = threadIdx.x >> 6;
    const int b  = blockIdx.x & 7;                  // XCD-pinned batch
    const int ng = blockIdx.x >> 3;                 // node group (0..2499)
    const int n  = ng * 4 + wave;
    const int e  = lane >> 4;                       // edge slot
    const int c  = lane & 15;                       // col chunk (8 bf16)
    const ushort_* __restrict__ hb = hw + (size_t)b * (N_ * H_) + c * 8;
    int o  = offsets[n];
    int dc = offsets[n + 1] - o;

    // hoisted epilogue operands (independent of the gather)
    float ni = norm_in[n];
    const int col = c * 8 + e * 2;
    const size_t off = ((size_t)b * N_ + n) * H_ + col;
    float2 hp = *(const float2*)(h_prev + off);
    float2 gb = *(const float2*)(gcn_b + col);
    float2 vr = *(const float2*)(xr + b * H_ + col);
    float2 vz = *(const float2*)(xz + b * H_ + col);
    float2 vh = *(const float2*)(xh + b * H_ + col);

    float a[8];
    #pragma unroll
    for (int k = 0; k < 8; ++k) a[k] = 0.f;
    for (int base = 0; base < dc; base += 64) {
        int rem = dc - base;
        int   sp = 0; float cp = 0.f;
        if (lane < rem) {                           // coef=0 past dc -> slots no-op
            sp = csr_src[o + base + lane];
            cp = csr_coef[o + base + lane];
        }
        int lim = rem < 64 ? rem : 64;
        for (int j = 0; j < lim; j += 16) {         // q = j+e+{0,4,8,12} < 64 always
            int   s0 = __shfl(sp, j + e);
            int   s1 = __shfl(sp, j + e + 4);
            int   s2 = __shfl(sp, j + e + 8);
            int   s3 = __shfl(sp, j + e + 12);
            float f0 = __shfl(cp, j + e);
            float f1 = __shfl(cp, j + e + 4);
            float f2 = __shfl(cp, j + e + 8);
            float f3 = __shfl(cp, j + e + 12);
            uint4 u0 = *(const uint4*)(hb + (size_t)s0 * H_);
            uint4 u1 = *(const uint4*)(hb + (size_t)s1 * H_);
            uint4 u2 = *(const uint4*)(hb + (size_t)s2 * H_);
            uint4 u3 = *(const uint4*)(hb + (size_t)s3 * H_);
            FMA8(a, f0, u0);
            FMA8(a, f1, u1);
            FMA8(a, f2, u2);
            FMA8(a, f3, u3);
        }
    }
    // fold the 4 edge slots (lane bits 4,5)
    #pragma unroll
    for (int k = 0; k < 8; ++k) {
        a[k] += __shfl_xor(a[k], 16);
        a[k] += __shfl_xor(a[k], 32);
    }
    // each lane finishes 2 columns: col = c*8 + e*2 (static acc selection)
    float a0 = (e == 0) ? a[0] : (e == 1) ? a[2] : (e == 2) ? a[4] : a[6];
    float a1 = (e == 0) ? a[1] : (e == 1) ? a[3] : (e == 2) ? a[5] : a[7];
    float2 wv;
    {
        float hc = a0 * ni + gb.x;
        float rr = sigmoidf_(vr.x + hc);
        float zz = sigmoidf_(vz.x + hc);
        float ht = tanh_fast(vh.x + rr * hc);
        wv.x = (1.f - zz) * hp.x + zz * ht;
    }
    {
        float hc = a1 * ni + gb.y;
        float rr = sigmoidf_(vr.y + hc);
        float zz = sigmoidf_(vz.y + hc);
        float ht = tanh_fast(vh.y + rr * hc);
        wv.y = (1.f - zz) * hp.y + zz * ht;
    }
    *(float2*)(out + off) = wv;
}

extern "C" void kernel_launch(void* const* d_in, const int* in_sizes, int n_in,
                              void* d_out, int out_size, void* d_ws, size_t ws_size,
                              hipStream_t stream) {
    (void)in_sizes; (void)n_in; (void)out_size; (void)ws_size;
    const float* x      = (const float*)d_in[0];
    const float* h_prev = (const float*)d_in[1];
    const int*   src    = (const int*)d_in[2];
    const int*   dst    = (const int*)d_in[3];
    const float* w_r    = (const float*)d_in[4];
    const float* b_r    = (const float*)d_in[5];
    const float* w_z    = (const float*)d_in[6];
    const float* b_z    = (const float*)d_in[7];
    const float* w_h    = (const float*)d_in[8];
    const float* b_h    = (const float*)d_in[9];
    const float* gcn_w  = (const float*)d_in[10];
    const float* gcn_b  = (const float*)d_in[11];
    float* out = (float*)d_out;

    ushort_* hw = (ushort_*)d_ws;                        // B*N*H bf16 = 20.48 MB
    int* wsi = (int*)(hw + (size_t)B_ * N_ * H_);
    int* out_deg   = wsi;                       // N
    int* in_deg    = wsi + N_;                  // N
    int* cursor    = wsi + 2 * N_;              // N
    int* offsets   = wsi + 3 * N_;              // N+1
    float* norm_out = (float*)(wsi + 4 * N_ + 1);  // N
    float* norm_in  = norm_out + N_;               // N
    int*   csr_src  = (int*)(norm_in + N_);        // E
    float* csr_coef = (float*)(csr_src + E_);      // E
    float* xr = csr_coef + E_;                     // B*H
    float* xz = xr + B_ * H_;
    float* xh = xz + B_ * H_;
    ushort_* wt = (ushort_*)(xh + B_ * H_);        // H*H bf16 = 32 KB

    hipMemsetAsync(out_deg, 0, 3 * N_ * sizeof(int), stream);  // out_deg, in_deg, cursor
    degrees_k<<<(E_ + 255) / 256, 256, 0, stream>>>(src, dst, out_deg, in_deg);
    norms_scan_k<<<1, 1024, 0, stream>>>(out_deg, in_deg, norm_out, norm_in, offsets);
    fill_csr_k<<<(E_ + 255) / 256, 256, 0, stream>>>(src, dst, offsets, cursor, norm_out, csr_src, csr_coef);
    xproj_k<<<dim3(4, B_), 256, 0, stream>>>(x, w_r, b_r, w_z, b_z, w_h, b_h, gcn_w, wt, xr, xz, xh);
    gemm_cast_k<<<dim3(8, 79), 256, 0, stream>>>(h_prev, wt, hw);
    agg_gru_k<<<(N_ / 4) * 8, 256, 0, stream>>>(hw, offsets, norm_in, csr_src, csr_coef,
                                                gcn_b, xr, xz, xh, h_prev, out);
}

// Round 6
// 114.299 us; speedup vs baseline: 1.2752x; 1.0865x over previous
//
#include <hip/hip_runtime.h>
#include <hip/hip_bf16.h>

#define B_   8
#define N_   10000
#define H_   128
#define DIN_ 256
#define E_   160000
#define EPAD_ (E_ + 7 * N_ + 8)   // padded CSR capacity (each bucket rounded to x8)

typedef unsigned int uint_;
typedef unsigned short ushort_;
typedef __attribute__((ext_vector_type(8))) short short8;
typedef __attribute__((ext_vector_type(4))) float f32x4;

__device__ __forceinline__ float sigmoidf_(float v) { return 1.f / (1.f + __expf(-v)); }
// tanh via exp, safe at +/-inf
__device__ __forceinline__ float tanh_fast(float v) { float e = __expf(2.f * v); return 1.f - 2.f / (e + 1.f); }

__device__ __forceinline__ ushort_ f2bf(float f) {
    union { float f; uint_ u; } v; v.f = f;
    uint_ r = v.u + 0x7fff + ((v.u >> 16) & 1);   // round-to-nearest-even
    return (ushort_)(r >> 16);
}
#define BF_LO(u) __uint_as_float((u) << 16)
#define BF_HI(u) __uint_as_float((u) & 0xffff0000u)

// ---- degrees ------------------------------------------------------------
__global__ __launch_bounds__(256) void degrees_k(const int* __restrict__ src, const int* __restrict__ dst,
                                                 int* __restrict__ out_deg, int* __restrict__ in_deg) {
    int e = blockIdx.x * 256 + threadIdx.x;
    if (e < E_) {
        atomicAdd(&out_deg[src[e]], 1);
        atomicAdd(&in_deg[dst[e]], 1);
    }
}

// ---- norms + exclusive scan of PADDED in_deg -> CSR row offsets ---------
// Buckets padded to x8 so agg's edge walk needs no bounds logic (pad slots
// are zero-filled by the memset: src=0, coef=0 -> FMA no-op).
// All global I/O coalesced (thread-contiguous chunks live only in LDS).
__global__ __launch_bounds__(1024) void norms_scan_k(const int* __restrict__ out_deg, const int* __restrict__ in_deg,
                                                     float* __restrict__ norm_out, float* __restrict__ norm_in,
                                                     int* __restrict__ offsets) {
    __shared__ int buf[10240];       // 40 KB
    __shared__ int part[1024];
    const int tid = threadIdx.x;
    // phase A: coalesced load of in_deg into LDS (padded) + coalesced norm writes
    #pragma unroll
    for (int q = 0; q < 10; ++q) {
        int idx = q * 1024 + tid;
        int d = (idx < N_) ? in_deg[idx] : 0;
        buf[idx] = (idx < N_) ? ((d + 7) & ~7) : 0;
        if (idx < N_) {
            int od = out_deg[idx];
            norm_out[idx] = od > 0 ? rsqrtf((float)od) : 0.f;
            norm_in[idx]  = d  > 0 ? rsqrtf((float)d)  : 0.f;
        }
    }
    __syncthreads();
    // phase B: per-thread scan of its contiguous 10-chunk (from LDS)
    int local[10];
    int s = 0;
    #pragma unroll
    for (int q = 0; q < 10; ++q) {
        local[q] = s;
        s += buf[tid * 10 + q];
    }
    part[tid] = s;
    __syncthreads();
    // phase C: block scan of partials
    for (int off = 1; off < 1024; off <<= 1) {
        int v = (tid >= off) ? part[tid - off] : 0;
        __syncthreads();
        part[tid] += v;
        __syncthreads();
    }
    int pre = (tid > 0) ? part[tid - 1] : 0;
    // phase D: write results into LDS, then coalesced store
    #pragma unroll
    for (int q = 0; q < 10; ++q)
        buf[tid * 10 + q] = pre + local[q];
    __syncthreads();
    #pragma unroll
    for (int q = 0; q < 10; ++q) {
        int idx = q * 1024 + tid;
        if (idx < N_) offsets[idx] = buf[idx];
    }
    if (tid == 1023) offsets[N_] = part[1023];
}

// ---- bucket-fill CSR: packed (src, coef) pairs --------------------------
__global__ __launch_bounds__(256) void fill_csr_k(const int* __restrict__ src, const int* __restrict__ dst,
                                                  const int* __restrict__ offsets, int* __restrict__ cursor,
                                                  const float* __restrict__ norm_out,
                                                  int2* __restrict__ csr_ed) {
    int e = blockIdx.x * 256 + threadIdx.x;
    if (e < E_) {
        int d = dst[e];
        int s = src[e];
        int pos = offsets[d] + atomicAdd(&cursor[d], 1);
        csr_ed[pos] = make_int2(s, __float_as_int(norm_out[s]));
    }
}

// ---- x projections + W^T cast: grid (4, 8); g==3 does wt transpose ------
__global__ __launch_bounds__(256) void xproj_k(const float* __restrict__ x,
                                               const float* __restrict__ w_r, const float* __restrict__ b_r,
                                               const float* __restrict__ w_z, const float* __restrict__ b_z,
                                               const float* __restrict__ w_h, const float* __restrict__ b_h,
                                               const float* __restrict__ gcn_w, ushort_* __restrict__ wt,
                                               float* __restrict__ xr, float* __restrict__ xz, float* __restrict__ xh) {
    const int g = blockIdx.x, b = blockIdx.y;
    if (g == 3) {                    // transpose + cast gcn_w (k,n) -> WT (n,k) bf16
        if (b != 0) return;
        const int t = threadIdx.x;
        const int n = t >> 1;
        const int kb = (t & 1) * 64;
        #pragma unroll
        for (int i = 0; i < 8; ++i) {
            int k = kb + i * 8;
            uint4 o;
            o.x = (uint_)f2bf(gcn_w[(k + 0) * H_ + n]) | ((uint_)f2bf(gcn_w[(k + 1) * H_ + n]) << 16);
            o.y = (uint_)f2bf(gcn_w[(k + 2) * H_ + n]) | ((uint_)f2bf(gcn_w[(k + 3) * H_ + n]) << 16);
            o.z = (uint_)f2bf(gcn_w[(k + 4) * H_ + n]) | ((uint_)f2bf(gcn_w[(k + 5) * H_ + n]) << 16);
            o.w = (uint_)f2bf(gcn_w[(k + 6) * H_ + n]) | ((uint_)f2bf(gcn_w[(k + 7) * H_ + n]) << 16);
            *(uint4*)(wt + n * H_ + k) = o;
        }
        return;
    }
    const float* __restrict__ w  = g == 0 ? w_r : (g == 1 ? w_z : w_h);
    const float* __restrict__ bs = g == 0 ? b_r : (g == 1 ? b_z : b_h);
    float* __restrict__ o        = g == 0 ? xr  : (g == 1 ? xz  : xh);
    const int k = threadIdx.x & 127, half = threadIdx.x >> 7;
    const float* xb = x + b * DIN_;
    float a = 0.f;
    #pragma unroll 8
    for (int d = half * 128; d < half * 128 + 128; ++d)
        a += xb[d] * w[d * H_ + k];
    __shared__ float part[2][128];
    part[half][k] = a;
    __syncthreads();
    if (half == 0) o[b * H_ + k] = a + part[1][k] + bs[k];
}

// ---- GEMM-first: hw = bf16(h_prev @ gcn_w) ------------------------------
// LDS-staged + batch-pinned grid (8, 79): blockIdx.x = batch -> hw slab
// written on the XCD agg reads it from. 2 node-tiles/block, WT staged once.
__global__ __launch_bounds__(256) void gemm_cast_k(const float* __restrict__ h,
                                                   const ushort_* __restrict__ wt,
                                                   ushort_* __restrict__ hw) {
    __shared__ ushort_ WT_s[H_ * H_];   // [n][k] bf16, swizzled: 32 KB
    __shared__ ushort_ A_s[64 * H_];    // [row][k] bf16, swizzled: 16 KB
    const int tid = threadIdx.x;
    const int b = blockIdx.x;           // batch (0..7) == XCD
    const size_t bslab = (size_t)b * N_;

    // stage W^T once: 2048 16B-chunks; swizzle k-ushorts by ((n&7)<<3)
    #pragma unroll
    for (int i = 0; i < 8; ++i) {
        int c = i * 256 + tid;
        int n = c >> 4;
        int kus = (c & 15) * 8;
        uint4 v = ((const uint4*)wt)[c];
        *(uint4*)&WT_s[n * H_ + (kus ^ ((n & 7) << 3))] = v;
    }

    const int l = tid & 63;
    const int w = tid >> 6;
    const int lr = l & 15;
    const int kg = (l >> 4) * 8;
    const int arow = w * 16 + lr;

    for (int t = blockIdx.y; t < 157; t += 79) {    // tiles 0..156 (157 = ceil(N/64))
        const int n0 = t * 64;
        // stage A tile: 64x128 fp32 rows of h -> bf16, swizzled (guarded)
        #pragma unroll
        for (int i = 0; i < 8; ++i) {
            int f4 = i * 256 + tid;           // float4 id within tile (0..2047)
            int row = f4 >> 5;
            int col4 = (f4 & 31) * 4;
            f32x4 v = {0.f, 0.f, 0.f, 0.f};
            if (n0 + row < N_) v = *(const f32x4*)&h[(bslab + n0 + row) * H_ + col4];
            uint2 p;
            p.x = (uint_)f2bf(v[0]) | ((uint_)f2bf(v[1]) << 16);
            p.y = (uint_)f2bf(v[2]) | ((uint_)f2bf(v[3]) << 16);
            *(uint2*)&A_s[row * H_ + (col4 ^ ((row & 7) << 3))] = p;
        }
        __syncthreads();

        f32x4 acc[8];
        #pragma unroll
        for (int nf = 0; nf < 8; ++nf) acc[nf] = (f32x4){0.f, 0.f, 0.f, 0.f};

        #pragma unroll
        for (int kk = 0; kk < 4; ++kk) {
            int kus = kk * 32 + kg;
            short8 av = *(const short8*)&A_s[arow * H_ + (kus ^ ((arow & 7) << 3))];
            #pragma unroll
            for (int nf = 0; nf < 8; ++nf) {
                int nrow = nf * 16 + lr;
                short8 bv = *(const short8*)&WT_s[nrow * H_ + (kus ^ ((nrow & 7) << 3))];
                acc[nf] = __builtin_amdgcn_mfma_f32_16x16x32_bf16(av, bv, acc[nf], 0, 0, 0);
            }
        }

        // epilogue: C/D layout col = lane&15, row = (lane>>4)*4 + r (m89).
        const int wrow0 = w * 16 + (l >> 4) * 4;
        #pragma unroll
        for (int nf = 0; nf < 8; ++nf) {
            int col = nf * 16 + lr;
            #pragma unroll
            for (int r = 0; r < 4; ++r) {
                int row = wrow0 + r;
                A_s[row * H_ + (col ^ ((row & 7) << 3))] = f2bf(acc[nf][r]);
            }
        }
        __syncthreads();   // cross-lane LDS transpose: make visibility explicit
        {
            int row = w * 16 + (l >> 2);      // 16 rows x 4 col-groups per wave
            int c0 = (l & 3) * 32;            // 32 ushorts = 64B per lane
            int swz = (row & 7) << 3;
            if (n0 + row < N_) {
                uint4 o0 = *(const uint4*)&A_s[row * H_ + ((c0 +  0) ^ swz)];
                uint4 o1 = *(const uint4*)&A_s[row * H_ + ((c0 +  8) ^ swz)];
                uint4 o2 = *(const uint4*)&A_s[row * H_ + ((c0 + 16) ^ swz)];
                uint4 o3 = *(const uint4*)&A_s[row * H_ + ((c0 + 24) ^ swz)];
                uint4* dst = (uint4*)(hw + (bslab + n0 + row) * (size_t)H_ + c0);
                dst[0] = o0; dst[1] = o1; dst[2] = o2; dst[3] = o3;
            }
        }
        __syncthreads();   // A_s reused next tile iteration
    }
}

// ---- aggregation of hw + fused GRU, one batch per XCD -------------------
// Wave = one (node, batch); batch = blockIdx.x & 7 pins each batch's 2.56MB
// hw slice to one XCD's L2. The edge walk is WAVE-UNIFORM: per-edge src is
// forced to SGPR (readfirstlane) so the gather is global_load_dword with a
// scalar base (all addressing on SALU), coef is a wave-uniform VGPR, and no
// cross-lane fold is needed (each lane owns 2 columns for the whole walk).
// CSR buckets padded to x8 with zero-coef entries -> no bounds logic.
__global__ __launch_bounds__(256) void agg_gru_k(const ushort_* __restrict__ hw, const int* __restrict__ offsets,
                                                 const float* __restrict__ norm_in,
                                                 const int2* __restrict__ csr_ed,
                                                 const float* __restrict__ gcn_b,
                                                 const float* __restrict__ xr, const float* __restrict__ xz,
                                                 const float* __restrict__ xh,
                                                 const float* __restrict__ h_prev, float* __restrict__ out) {
    const int lane = threadIdx.x & 63;
    const int wave = threadIdx.x >> 6;
    const int b  = blockIdx.x & 7;                  // XCD-pinned batch
    const int ng = blockIdx.x >> 3;                 // node group (0..2499)
    const int n  = ng * 4 + wave;
    const int o  = __builtin_amdgcn_readfirstlane(offsets[n]);
    const int dc = __builtin_amdgcn_readfirstlane(offsets[n + 1]) - o;   // multiple of 8
    const int2* __restrict__ ed = csr_ed + o;
    const ushort_* __restrict__ hb = hw + (size_t)b * (N_ * H_) + lane * 2;

    // hoisted epilogue operands (latency overlaps the gather walk)
    const float ni = norm_in[n];
    const int col = lane * 2;
    const size_t off = ((size_t)b * N_ + n) * H_ + col;
    float2 hp = *(const float2*)(h_prev + off);
    float2 gb = *(const float2*)(gcn_b + col);
    float2 vr = *(const float2*)(xr + b * H_ + col);
    float2 vz = *(const float2*)(xz + b * H_ + col);
    float2 vh = *(const float2*)(xh + b * H_ + col);

    float a0 = 0.f, a1 = 0.f;
    for (int j = 0; j < dc; j += 8) {
        #pragma unroll
        for (int q = 0; q < 8; ++q) {
            int2 eq = ed[j + q];                                  // uniform addr
            int   s = __builtin_amdgcn_readfirstlane(eq.x);       // SGPR src
            float c = __uint_as_float((uint_)eq.y);               // uniform coef
            uint_ u = *(const uint_*)(hb + (size_t)s * H_);       // 2 bf16/lane
            a0 += c * BF_LO(u);
            a1 += c * BF_HI(u);
        }
    }

    float2 wv;
    {
        float hc = a0 * ni + gb.x;
        float rr = sigmoidf_(vr.x + hc);
        float zz = sigmoidf_(vz.x + hc);
        float ht = tanh_fast(vh.x + rr * hc);
        wv.x = (1.f - zz) * hp.x + zz * ht;
    }
    {
        float hc = a1 * ni + gb.y;
        float rr = sigmoidf_(vr.y + hc);
        float zz = sigmoidf_(vz.y + hc);
        float ht = tanh_fast(vh.y + rr * hc);
        wv.y = (1.f - zz) * hp.y + zz * ht;
    }
    *(float2*)(out + off) = wv;
}

extern "C" void kernel_launch(void* const* d_in, const int* in_sizes, int n_in,
                              void* d_out, int out_size, void* d_ws, size_t ws_size,
                              hipStream_t stream) {
    (void)in_sizes; (void)n_in; (void)out_size; (void)ws_size;
    const float* x      = (const float*)d_in[0];
    const float* h_prev = (const float*)d_in[1];
    const int*   src    = (const int*)d_in[2];
    const int*   dst    = (const int*)d_in[3];
    const float* w_r    = (const float*)d_in[4];
    const float* b_r    = (const float*)d_in[5];
    const float* w_z    = (const float*)d_in[6];
    const float* b_z    = (const float*)d_in[7];
    const float* w_h    = (const float*)d_in[8];
    const float* b_h    = (const float*)d_in[9];
    const float* gcn_w  = (const float*)d_in[10];
    const float* gcn_b  = (const float*)d_in[11];
    float* out = (float*)d_out;

    ushort_* hw = (ushort_*)d_ws;                  // B*N*H bf16 = 20.48 MB
    int* wsi = (int*)(hw + (size_t)B_ * N_ * H_);
    int* out_deg   = wsi;                          // N
    int* in_deg    = wsi + N_;                     // N
    int* cursor    = wsi + 2 * N_;                 // N
    int2* csr_ed   = (int2*)(wsi + 3 * N_);        // EPAD_ packed (src, coef)
    int* offsets   = (int*)(csr_ed + EPAD_);       // N+1
    float* norm_out = (float*)(offsets + N_ + 1);  // N
    float* norm_in  = norm_out + N_;               // N
    float* xr = norm_in + N_;                      // B*H
    float* xz = xr + B_ * H_;
    float* xh = xz + B_ * H_;
    ushort_* wt = (ushort_*)(xh + B_ * H_);        // H*H bf16 = 32 KB

    // zero out_deg, in_deg, cursor AND the padded CSR (pad slots: src=0, coef=0)
    hipMemsetAsync(out_deg, 0, 3 * N_ * sizeof(int) + EPAD_ * sizeof(int2), stream);
    degrees_k<<<(E_ + 255) / 256, 256, 0, stream>>>(src, dst, out_deg, in_deg);
    norms_scan_k<<<1, 1024, 0, stream>>>(out_deg, in_deg, norm_out, norm_in, offsets);
    fill_csr_k<<<(E_ + 255) / 256, 256, 0, stream>>>(src, dst, offsets, cursor, norm_out, csr_ed);
    xproj_k<<<dim3(4, B_), 256, 0, stream>>>(x, w_r, b_r, w_z, b_z, w_h, b_h, gcn_w, wt, xr, xz, xh);
    gemm_cast_k<<<dim3(8, 79), 256, 0, stream>>>(h_prev, wt, hw);
    agg_gru_k<<<(N_ / 4) * 8, 256, 0, stream>>>(hw, offsets, norm_in, csr_ed,
                                                gcn_b, xr, xz, xh, h_prev, out);
}